// Round 6
// baseline (118.977 us; speedup 1.0000x reference)
//
#include <hip/hip_runtime.h>

typedef __attribute__((ext_vector_type(8))) short bf16x8;
typedef __attribute__((ext_vector_type(4))) float f32x4;
typedef __attribute__((ext_vector_type(4))) unsigned short us4;

__device__ __forceinline__ unsigned short f2bf(float f) {
    unsigned int u = __builtin_bit_cast(unsigned int, f);
    u = (u + 0x7FFFu + ((u >> 16) & 1u)) >> 16;
    return (unsigned short)u;
}
__device__ __forceinline__ float bf2f(unsigned short h) {
    return __builtin_bit_cast(float, (unsigned int)h << 16);
}

// ---------------- fold BN into weights, emit bf16 ----------------
__global__ __launch_bounds__(256) void fold_weights_k(
    const float* __restrict__ Wq, const float* __restrict__ sq, const float* __restrict__ bq,
    const float* __restrict__ Wk, const float* __restrict__ sk, const float* __restrict__ bk,
    const float* __restrict__ Wv, const float* __restrict__ sv, const float* __restrict__ bv,
    const float* __restrict__ Wp, const float* __restrict__ sp,
    unsigned short* __restrict__ Wqkv, unsigned short* __restrict__ Wpf, float* __restrict__ bqkv)
{
    int i = blockIdx.x * 256 + threadIdx.x;
    if (i < 393216) {                       // Wqkv [1024][384]
        int o = i / 384;
        float w, s;
        if (o < 256)      { w = Wq[i];                s = sq[o]; }
        else if (o < 512) { w = Wk[i - 256 * 384];    s = sk[o - 256]; }
        else              { w = Wv[i - 512 * 384];    s = sv[o - 512]; }
        Wqkv[i] = f2bf(w * s);
    } else if (i < 589824) {                // Wpf [384][512]
        int j = i - 393216;
        Wpf[j] = f2bf(Wp[j] * sp[j >> 9]);
    } else if (i < 590848) {
        int o = i - 589824;
        bqkv[o] = (o < 256) ? bq[o] : (o < 512 ? bk[o - 256] : bv[o - 512]);
    }
}

// ---------------- x [b][384][4096] f32 -> xT [b][4096][384] bf16 (vectorized) ----------------
__global__ __launch_bounds__(256) void transpose_x_k(const float* __restrict__ x,
                                                     unsigned short* __restrict__ xT)
{
    __shared__ unsigned short t[64][72];
    const int b = blockIdx.z, cb = blockIdx.y << 6, nb = blockIdx.x << 6;
    const int tid = threadIdx.x;
    const float* xb = x + ((long)b * 384 + cb) * 4096 + nb;
    const int n4 = (tid & 15) * 4;
    #pragma unroll
    for (int p = 0; p < 4; ++p) {
        int c = (tid >> 4) + p * 16;
        float4 v = *reinterpret_cast<const float4*>(xb + (long)c * 4096 + n4);
        us4 o = { f2bf(v.x), f2bf(v.y), f2bf(v.z), f2bf(v.w) };
        *reinterpret_cast<us4*>(&t[c][n4]) = o;
    }
    __syncthreads();
    const int c4 = (tid & 15) * 4;
    unsigned short* ob = xT + ((long)b * 4096 + nb) * 384 + cb;
    #pragma unroll
    for (int p = 0; p < 4; ++p) {
        int n = (tid >> 4) + p * 16;
        us4 o = { t[c4][n], t[c4 + 1][n], t[c4 + 2][n], t[c4 + 3][n] };
        *reinterpret_cast<us4*>(ob + (long)n * 384 + c4) = o;
    }
}

// ---------------- QKV GEMM: 256^2 tile, BK=32, 4-buffer counted-vmcnt pipeline ----------------
// grid (16 n, 4 m, 8 b), 512 threads = 8 waves (2M x 4N). LDS 128 KB -> 1 block/CU.
// Tile k lives in buf k&3; while computing tile k we stage tile k+3 into buf (k-1)&3,
// whose readers finished before the tile-k start barrier. Steady-state wait: vmcnt(8).
__global__ __launch_bounds__(512, 2) void gemm_qkv_k(
    const unsigned short* __restrict__ A,     // Wqkv [1024][384]
    const unsigned short* __restrict__ Bt,    // xT   [b][4096][384]
    const float* __restrict__ bias,
    unsigned short* __restrict__ q_out,
    unsigned short* __restrict__ kv_out)
{
    __shared__ unsigned short As[4 * 8192];   // 4 bufs x 256 rows x 32 k
    __shared__ unsigned short Bs[4 * 8192];
    const int tid = threadIdx.x;
    const int lane = tid & 63;
    const int w = tid >> 6, wr = w >> 2, wc = w & 3;
    const int li = lane & 15, g = lane >> 4;
    const int b = blockIdx.z;
    const int n0 = blockIdx.x * 256, m0 = blockIdx.y * 256;
    const unsigned short* Bb = Bt + (long)b * 4096 * 384;

    // stage source pre-permutation (involution with the read swizzle)
    const int sidx0 = tid,        sr0 = sidx0 >> 2;
    const int sidx1 = 512 + tid,  sr1 = sidx1 >> 2;
    const int ssl0 = ((sidx0 & 3) ^ (sr0 & 3) ^ ((sr0 >> 2) & 3)) * 8;
    const int ssl1 = ((sidx1 & 3) ^ (sr1 & 3) ^ ((sr1 >> 2) & 3)) * 8;

#define STAGE_A(kt) { int _bf = (kt) & 3; int _k0 = (kt) * 32; \
    __builtin_amdgcn_global_load_lds( \
        (const __attribute__((address_space(1))) void*)(A + (long)(m0 + sr0) * 384 + _k0 + ssl0), \
        (__attribute__((address_space(3))) void*)(As + _bf * 8192 + (size_t)sidx0 * 8), 16, 0, 0); \
    __builtin_amdgcn_global_load_lds( \
        (const __attribute__((address_space(1))) void*)(A + (long)(m0 + sr1) * 384 + _k0 + ssl1), \
        (__attribute__((address_space(3))) void*)(As + _bf * 8192 + (size_t)sidx1 * 8), 16, 0, 0); }
#define STAGE_B(kt) { int _bf = (kt) & 3; int _k0 = (kt) * 32; \
    __builtin_amdgcn_global_load_lds( \
        (const __attribute__((address_space(1))) void*)(Bb + (long)(n0 + sr0) * 384 + _k0 + ssl0), \
        (__attribute__((address_space(3))) void*)(Bs + _bf * 8192 + (size_t)sidx0 * 8), 16, 0, 0); \
    __builtin_amdgcn_global_load_lds( \
        (const __attribute__((address_space(1))) void*)(Bb + (long)(n0 + sr1) * 384 + _k0 + ssl1), \
        (__attribute__((address_space(3))) void*)(Bs + _bf * 8192 + (size_t)sidx1 * 8), 16, 0, 0); }

    // prologue: stage tiles 0,1,2 (12 loads/thread in flight)
    #pragma unroll
    for (int kt = 0; kt < 3; ++kt) { STAGE_A(kt); STAGE_B(kt); }

    f32x4 acc[8][4];
    #pragma unroll
    for (int i = 0; i < 8; ++i)
        #pragma unroll
        for (int j = 0; j < 4; ++j) acc[i][j] = (f32x4){0.f, 0.f, 0.f, 0.f};

    #pragma unroll
    for (int kt = 0; kt < 12; ++kt) {
        // tile-start: counted drain of THIS tile's 4 loads (cross-wave via barrier)
        if (kt <= 9)       asm volatile("s_waitcnt vmcnt(8)\n\ts_barrier" ::: "memory");
        else if (kt == 10) asm volatile("s_waitcnt vmcnt(4)\n\ts_barrier" ::: "memory");
        else               asm volatile("s_waitcnt vmcnt(0)\n\ts_barrier" ::: "memory");

        const unsigned short* Ab = As + (kt & 3) * 8192;
        const unsigned short* Bbf = Bs + (kt & 3) * 8192;

        // ---- phase 0: B frags + A frags m0-3, stage A of tile kt+3, 16 MFMA
        bf16x8 bv[4], av[4];
        #pragma unroll
        for (int nf = 0; nf < 4; ++nf) {
            int r = wc * 64 + nf * 16 + li;
            bv[nf] = *reinterpret_cast<const bf16x8*>(
                Bbf + r * 32 + ((g ^ (r & 3) ^ ((r >> 2) & 3)) * 8));
        }
        #pragma unroll
        for (int mf = 0; mf < 4; ++mf) {
            int r = wr * 128 + mf * 16 + li;
            av[mf] = *reinterpret_cast<const bf16x8*>(
                Ab + r * 32 + ((g ^ (r & 3) ^ ((r >> 2) & 3)) * 8));
        }
        if (kt < 9) STAGE_A(kt + 3);
        __builtin_amdgcn_s_setprio(1);
        #pragma unroll
        for (int mf = 0; mf < 4; ++mf)
            #pragma unroll
            for (int nf = 0; nf < 4; ++nf)
                acc[mf][nf] = __builtin_amdgcn_mfma_f32_16x16x32_bf16(av[mf], bv[nf], acc[mf][nf], 0, 0, 0);
        __builtin_amdgcn_s_setprio(0);
        asm volatile("s_barrier" ::: "memory");

        // ---- phase 1: A frags m4-7, stage B of tile kt+3, 16 MFMA
        bf16x8 av2[4];
        #pragma unroll
        for (int mf = 0; mf < 4; ++mf) {
            int r = wr * 128 + 64 + mf * 16 + li;
            av2[mf] = *reinterpret_cast<const bf16x8*>(
                Ab + r * 32 + ((g ^ (r & 3) ^ ((r >> 2) & 3)) * 8));
        }
        if (kt < 9) STAGE_B(kt + 3);
        __builtin_amdgcn_s_setprio(1);
        #pragma unroll
        for (int mf = 0; mf < 4; ++mf)
            #pragma unroll
            for (int nf = 0; nf < 4; ++nf)
                acc[mf + 4][nf] = __builtin_amdgcn_mfma_f32_16x16x32_bf16(av2[mf], bv[nf], acc[mf + 4][nf], 0, 0, 0);
        __builtin_amdgcn_s_setprio(0);
        // next tile-start barrier closes this phase
    }
#undef STAGE_A
#undef STAGE_B

    // ---- epilogue: blockIdx.y==0 -> q (transposed packed), else k/v channel-major
    #pragma unroll
    for (int mf = 0; mf < 8; ++mf) {
        int m = m0 + wr * 128 + mf * 16 + g * 4;
        #pragma unroll
        for (int nf = 0; nf < 4; ++nf) {
            int n = n0 + wc * 64 + nf * 16 + li;
            f32x4 v = acc[mf][nf];
            if (blockIdx.y == 0) {
                us4 o = { f2bf(v.x + bias[m]),     f2bf(v.y + bias[m + 1]),
                          f2bf(v.z + bias[m + 2]), f2bf(v.w + bias[m + 3]) };
                *reinterpret_cast<us4*>(q_out + (((long)b * 4096 + n) << 8) + m) = o;
            } else {
                #pragma unroll
                for (int r = 0; r < 4; ++r)
                    kv_out[((long)b * 768 + (m - 256 + r)) * 4096 + n] = f2bf(v[r] + bias[m + r]);
            }
        }
    }
}

// ---------------- key row stats: max + 1/sum(exp) per k row ----------------
__global__ __launch_bounds__(256) void key_stats_k(const unsigned short* __restrict__ kv,
                                                   float2* __restrict__ kstats)
{
    __shared__ float red[256];
    const int row = blockIdx.x;             // 0..2047 = b*256 + ch
    const unsigned short* p = kv + ((long)(row >> 8) * 768 + (row & 255)) * 4096;
    const int tid = threadIdx.x;
    us4 u[4];
    float f[16];
    #pragma unroll
    for (int i = 0; i < 4; ++i) u[i] = *reinterpret_cast<const us4*>(p + tid * 16 + i * 4);
    float mx = -1e30f;
    #pragma unroll
    for (int i = 0; i < 4; ++i)
        #pragma unroll
        for (int j = 0; j < 4; ++j) { f[i * 4 + j] = bf2f(u[i][j]); mx = fmaxf(mx, f[i * 4 + j]); }
    red[tid] = mx; __syncthreads();
    for (int s = 128; s > 0; s >>= 1) { if (tid < s) red[tid] = fmaxf(red[tid], red[tid + s]); __syncthreads(); }
    mx = red[0]; __syncthreads();
    float sum = 0.f;
    #pragma unroll
    for (int i = 0; i < 16; ++i) sum += __expf(f[i] - mx);
    red[tid] = sum; __syncthreads();
    for (int s = 128; s > 0; s >>= 1) { if (tid < s) red[tid] += red[tid + s]; __syncthreads(); }
    if (tid == 0) kstats[row] = make_float2(mx, 1.f / red[0]);
}

// ---------------- context partials with in-register exp: part += exp(k-mx)*v ----------------
__global__ __launch_bounds__(256) void context_k(const unsigned short* __restrict__ kv,
                                                 const float2* __restrict__ kstats,
                                                 float* __restrict__ part)
{
    __shared__ float lds[4][2048];
    const int bh = blockIdx.y, ck = blockIdx.x;
    const int b = bh >> 3, h = bh & 7;
    const int tid = threadIdx.x, lane = tid & 63, w = tid >> 6;
    const int li = lane & 15, g = lane >> 4;
    const unsigned short* kb = kv + ((long)b * 768 + h * 32) * 4096;
    const unsigned short* vb = kv + ((long)b * 768 + 256 + h * 64) * 4096;
    const float mx0 = kstats[b * 256 + h * 32 + li].x;
    const float mx1 = kstats[b * 256 + h * 32 + 16 + li].x;
    f32x4 acc[2][4];
    #pragma unroll
    for (int i = 0; i < 2; ++i)
        #pragma unroll
        for (int j = 0; j < 4; ++j) acc[i][j] = (f32x4){0.f, 0.f, 0.f, 0.f};

    const int nb0 = ck * 512 + w * 128 + g * 8;
    #pragma unroll
    for (int t = 0; t < 4; ++t) {
        int nb = nb0 + t * 32;
        bf16x8 r0 = *reinterpret_cast<const bf16x8*>(kb + (long)li * 4096 + nb);
        bf16x8 r1 = *reinterpret_cast<const bf16x8*>(kb + (long)(16 + li) * 4096 + nb);
        bf16x8 a0, a1;
        #pragma unroll
        for (int j = 0; j < 8; ++j) {
            a0[j] = (short)f2bf(__expf(bf2f((unsigned short)r0[j]) - mx0));
            a1[j] = (short)f2bf(__expf(bf2f((unsigned short)r1[j]) - mx1));
        }
        #pragma unroll
        for (int nf = 0; nf < 4; ++nf) {
            bf16x8 bv = *reinterpret_cast<const bf16x8*>(vb + (long)(nf * 16 + li) * 4096 + nb);
            acc[0][nf] = __builtin_amdgcn_mfma_f32_16x16x32_bf16(a0, bv, acc[0][nf], 0, 0, 0);
            acc[1][nf] = __builtin_amdgcn_mfma_f32_16x16x32_bf16(a1, bv, acc[1][nf], 0, 0, 0);
        }
    }
    #pragma unroll
    for (int mf = 0; mf < 2; ++mf)
        #pragma unroll
        for (int nf = 0; nf < 4; ++nf)
            #pragma unroll
            for (int r = 0; r < 4; ++r) {
                int kd = mf * 16 + g * 4 + r, d = nf * 16 + li;
                lds[w][kd * 64 + d] = acc[mf][nf][r];
            }
    __syncthreads();
    for (int i = tid; i < 2048; i += 256)
        part[((long)ck * 64 + bh) * 2048 + i] = lds[0][i] + lds[1][i] + lds[2][i] + lds[3][i];
}

// ---------------- reduce partials, apply 1/sum -> ctxT[bh][d][kd] bf16 ----------------
__global__ __launch_bounds__(256) void ctx_reduce_k(const float* __restrict__ part,
                                                    const float2* __restrict__ kstats,
                                                    unsigned short* __restrict__ ctxT)
{
    int t = blockIdx.x * 256 + threadIdx.x;   // < 131072
    int bh = t >> 11, i = t & 2047;
    int kd = i & 31;
    float s = 0.f;
    #pragma unroll
    for (int c = 0; c < 8; ++c) s += part[((long)c * 64 + bh) * 2048 + kd * 64 + (i >> 5)];
    ctxT[t] = f2bf(s * kstats[bh * 32 + kd].y);
}

// ---------------- fused proj v3: tall-M block (M=384), softmax+attend once, GEMM ----------------
// grid (32 n-blocks, 8 b), 512 threads = 8 waves. LDS = 112 KB -> 1 block/CU.
__global__ __launch_bounds__(512, 2) void proj_fused_k(
    const unsigned short* __restrict__ Wpf,   // [384][512] bf16, k = h*64+d
    const unsigned short* __restrict__ qT,    // [b][4096][256] bf16 (raw q, pre-softmax)
    const unsigned short* __restrict__ ctxT,  // [b*8+h][64 d][32 kd] bf16
    const float* __restrict__ bp,
    float* __restrict__ out)                  // [b][384][4096] f32
{
    __shared__ unsigned short Bsh[128 * 64];  // relu(attend) tile for current head, swizzled
    __shared__ unsigned short As[2][384 * 64];
    const int tid = threadIdx.x, lane = tid & 63, w = tid >> 6;
    const int li = lane & 15, g = lane >> 4;
    const int b = blockIdx.y, n0 = blockIdx.x * 128;

#define PROJ_STAGE(buf, s) { \
    _Pragma("unroll") \
    for (int j = 0; j < 6; ++j) { \
        int idx = j * 512 + tid; \
        int r = idx >> 3; \
        int ls = ((idx & 7) ^ (r & 7)) * 8; \
        __builtin_amdgcn_global_load_lds( \
            (const __attribute__((address_space(1))) void*)(Wpf + (long)r * 512 + (s) * 64 + ls), \
            (__attribute__((address_space(3))) void*)(As[buf] + (size_t)idx * 8), 16, 0, 0); \
    } }

    PROJ_STAGE(0, 0);

    f32x4 acc[3][8];
    #pragma unroll
    for (int i = 0; i < 3; ++i)
        #pragma unroll
        for (int j = 0; j < 8; ++j) acc[i][j] = (f32x4){0.f, 0.f, 0.f, 0.f};

    for (int s = 0; s < 8; ++s) {               // K-step s == head s
        // ---- attend (once per block): A = ctxT_s, B = softmax(q) in-register.
        const unsigned short* cb = ctxT + ((long)b * 8 + s) * 2048;
        bf16x8 ca[4], pb;
        #pragma unroll
        for (int df = 0; df < 4; ++df)
            ca[df] = *reinterpret_cast<const bf16x8*>(cb + (df * 16 + li) * 32 + g * 8);
        {
            int n = n0 + w * 16 + li;
            bf16x8 r = *reinterpret_cast<const bf16x8*>(
                qT + (((long)b * 4096 + n) << 8) + s * 32 + g * 8);
            float f[8];
            float mx = -1e30f;
            #pragma unroll
            for (int j = 0; j < 8; ++j) { f[j] = bf2f((unsigned short)r[j]); mx = fmaxf(mx, f[j]); }
            mx = fmaxf(mx, __shfl_xor(mx, 16));
            mx = fmaxf(mx, __shfl_xor(mx, 32));
            float sm = 0.f;
            #pragma unroll
            for (int j = 0; j < 8; ++j) { f[j] = __expf(f[j] - mx); sm += f[j]; }
            sm += __shfl_xor(sm, 16);
            sm += __shfl_xor(sm, 32);
            float inv = 1.f / sm;
            #pragma unroll
            for (int j = 0; j < 8; ++j) pb[j] = (short)f2bf(f[j] * inv);
        }
        us4 bw[4];
        #pragma unroll
        for (int df = 0; df < 4; ++df) {
            f32x4 d = (f32x4){0.f, 0.f, 0.f, 0.f};
            d = __builtin_amdgcn_mfma_f32_16x16x32_bf16(ca[df], pb, d, 0, 0, 0);
            bw[df] = (us4){ f2bf(fmaxf(d.x, 0.f)), f2bf(fmaxf(d.y, 0.f)),
                            f2bf(fmaxf(d.z, 0.f)), f2bf(fmaxf(d.w, 0.f)) };
        }

        __syncthreads();   // (A) prior step's Bsh/As reads done; As[s&1] data landed (vmcnt0)

        if (s < 7) PROJ_STAGE((s + 1) & 1, s + 1);   // As[(s+1)&1] readers finished at (A)

        // ---- write relu(attend) tile swizzled: Bsh[n][d], granule-8 XOR by (n&7)
        #pragma unroll
        for (int df = 0; df < 4; ++df) {
            int n = w * 16 + li;
            int slot = (df * 2 + (g >> 1)) ^ (n & 7);
            *reinterpret_cast<us4*>(Bsh + n * 64 + slot * 8 + (g & 1) * 4) = bw[df];
        }

        // (B) lgkm-only barrier: Bsh visible, As[(s+1)&1] stage stays in flight (T4)
        asm volatile("s_waitcnt lgkmcnt(0)\n\ts_barrier" ::: "memory");
        __builtin_amdgcn_sched_barrier(0);

        // ---- main GEMM MFMAs: wave w owns m-rows w*48..w*48+48 x n 0..128
        const unsigned short* Ab = As[s & 1];
        #pragma unroll
        for (int kk = 0; kk < 2; ++kk) {
            bf16x8 av[3], bv[8];
            #pragma unroll
            for (int mf = 0; mf < 3; ++mf) {
                int row = w * 48 + mf * 16 + li;
                int ps = ((kk * 4 + g) ^ (row & 7)) * 8;
                av[mf] = *reinterpret_cast<const bf16x8*>(Ab + row * 64 + ps);
            }
            #pragma unroll
            for (int nf = 0; nf < 8; ++nf) {
                int nn = nf * 16 + li;
                int ps = ((kk * 4 + g) ^ (nn & 7)) * 8;
                bv[nf] = *reinterpret_cast<const bf16x8*>(Bsh + nn * 64 + ps);
            }
            #pragma unroll
            for (int mf = 0; mf < 3; ++mf)
                #pragma unroll
                for (int nf = 0; nf < 8; ++nf)
                    acc[mf][nf] = __builtin_amdgcn_mfma_f32_16x16x32_bf16(av[mf], bv[nf], acc[mf][nf], 0, 0, 0);
        }
    }
#undef PROJ_STAGE

    #pragma unroll
    for (int mf = 0; mf < 3; ++mf) {
        int m = w * 48 + mf * 16 + g * 4;
        #pragma unroll
        for (int nf = 0; nf < 8; ++nf) {
            int n = n0 + nf * 16 + li;
            f32x4 v = acc[mf][nf];
            #pragma unroll
            for (int r = 0; r < 4; ++r)
                out[((long)b * 384 + m + r) * 4096 + n] = v[r] + bp[m + r];
        }
    }
}

// ---------------- launch ----------------
extern "C" void kernel_launch(void* const* d_in, const int* in_sizes, int n_in,
                              void* d_out, int out_size, void* d_ws, size_t ws_size,
                              hipStream_t stream) {
    (void)in_sizes; (void)n_in; (void)out_size; (void)ws_size;
    const float* x  = (const float*)d_in[0];
    const float* Wq = (const float*)d_in[1];
    const float* sq = (const float*)d_in[2];
    const float* bq = (const float*)d_in[3];
    const float* Wk = (const float*)d_in[4];
    const float* sk = (const float*)d_in[5];
    const float* bk = (const float*)d_in[6];
    const float* Wv = (const float*)d_in[7];
    const float* sv = (const float*)d_in[8];
    const float* bv = (const float*)d_in[9];
    const float* Wp = (const float*)d_in[10];
    const float* sp = (const float*)d_in[11];
    const float* bp = (const float*)d_in[12];
    float* out = (float*)d_out;

    char* wsb = (char*)d_ws;
    unsigned short* Wqkv  = (unsigned short*)(wsb);              // 786432 B
    unsigned short* Wpf   = (unsigned short*)(wsb + 786432);     // 393216 B
    float*          bqkv  = (float*)(wsb + 1179648);             // 4096 B
    unsigned short* ctxT  = (unsigned short*)(wsb + 1183744);    // 262144 B
    float*          part  = (float*)(wsb + 1445888);             // 4194304 B
    float2*         kstats= (float2*)(wsb + 5640192);            // 16384 B
    unsigned short* xT    = (unsigned short*)(wsb + 5656576);    // 25165824 B
    unsigned short* qT    = (unsigned short*)(wsb + 30822400);   // 16777216 B
    unsigned short* kv    = (unsigned short*)(wsb + 47599616);   // 50331648 B -> ~98 MB total

    fold_weights_k<<<2308, 256, 0, stream>>>(Wq, sq, bq, Wk, sk, bk, Wv, sv, bv, Wp, sp,
                                             Wqkv, Wpf, bqkv);
    transpose_x_k<<<dim3(64, 6, 8), 256, 0, stream>>>(x, xT);
    gemm_qkv_k<<<dim3(16, 4, 8), 512, 0, stream>>>(Wqkv, xT, bqkv, qT, kv);
    key_stats_k<<<2048, 256, 0, stream>>>(kv, kstats);
    context_k<<<dim3(8, 64), 256, 0, stream>>>(kv, kstats, part);
    ctx_reduce_k<<<512, 256, 0, stream>>>(part, kstats, ctxT);
    proj_fused_k<<<dim3(32, 8), 512, 0, stream>>>(Wpf, qT, ctxT, bp, out);
}

// Round 7
// 118.744 us; speedup vs baseline: 1.0020x; 1.0020x over previous
//
#include <hip/hip_runtime.h>

typedef __attribute__((ext_vector_type(8))) short bf16x8;
typedef __attribute__((ext_vector_type(4))) float f32x4;
typedef __attribute__((ext_vector_type(4))) unsigned short us4;

__device__ __forceinline__ unsigned short f2bf(float f) {
    unsigned int u = __builtin_bit_cast(unsigned int, f);
    u = (u + 0x7FFFu + ((u >> 16) & 1u)) >> 16;
    return (unsigned short)u;
}
__device__ __forceinline__ float bf2f(unsigned short h) {
    return __builtin_bit_cast(float, (unsigned int)h << 16);
}

// ---------------- fold BN into weights, emit bf16 ----------------
__global__ __launch_bounds__(256) void fold_weights_k(
    const float* __restrict__ Wq, const float* __restrict__ sq, const float* __restrict__ bq,
    const float* __restrict__ Wk, const float* __restrict__ sk, const float* __restrict__ bk,
    const float* __restrict__ Wv, const float* __restrict__ sv, const float* __restrict__ bv,
    const float* __restrict__ Wp, const float* __restrict__ sp,
    unsigned short* __restrict__ Wqkv, unsigned short* __restrict__ Wpf, float* __restrict__ bqkv)
{
    int i = blockIdx.x * 256 + threadIdx.x;
    if (i < 393216) {                       // Wqkv [1024][384]
        int o = i / 384;
        float w, s;
        if (o < 256)      { w = Wq[i];                s = sq[o]; }
        else if (o < 512) { w = Wk[i - 256 * 384];    s = sk[o - 256]; }
        else              { w = Wv[i - 512 * 384];    s = sv[o - 512]; }
        Wqkv[i] = f2bf(w * s);
    } else if (i < 589824) {                // Wpf [384][512]
        int j = i - 393216;
        Wpf[j] = f2bf(Wp[j] * sp[j >> 9]);
    } else if (i < 590848) {
        int o = i - 589824;
        bqkv[o] = (o < 256) ? bq[o] : (o < 512 ? bk[o - 256] : bv[o - 512]);
    }
}

// ---------------- x [b][384][4096] f32 -> xT [b][4096][384] bf16 (vectorized) ----------------
__global__ __launch_bounds__(256) void transpose_x_k(const float* __restrict__ x,
                                                     unsigned short* __restrict__ xT)
{
    __shared__ unsigned short t[64][72];
    const int b = blockIdx.z, cb = blockIdx.y << 6, nb = blockIdx.x << 6;
    const int tid = threadIdx.x;
    const float* xb = x + ((long)b * 384 + cb) * 4096 + nb;
    const int n4 = (tid & 15) * 4;
    #pragma unroll
    for (int p = 0; p < 4; ++p) {
        int c = (tid >> 4) + p * 16;
        float4 v = *reinterpret_cast<const float4*>(xb + (long)c * 4096 + n4);
        us4 o = { f2bf(v.x), f2bf(v.y), f2bf(v.z), f2bf(v.w) };
        *reinterpret_cast<us4*>(&t[c][n4]) = o;
    }
    __syncthreads();
    const int c4 = (tid & 15) * 4;
    unsigned short* ob = xT + ((long)b * 4096 + nb) * 384 + cb;
    #pragma unroll
    for (int p = 0; p < 4; ++p) {
        int n = (tid >> 4) + p * 16;
        us4 o = { t[c4][n], t[c4 + 1][n], t[c4 + 2][n], t[c4 + 3][n] };
        *reinterpret_cast<us4*>(ob + (long)n * 384 + c4) = o;
    }
}

// ---------------- QKV GEMM: 128x256 tile, BK=64, 3-buffer counted-vmcnt pipeline ----------------
// grid (16 n, 8 m, 8 b), 512 threads = 8 waves (2M x 4N), wave tile 64x64.
// LDS = 3 x (A 16KB + B 32KB) = 144 KB -> 1 block/CU. Proven (r&7) granule-8 XOR swizzle.
// Tile t lives in buf t%3; during tile t we stage tile t+2 into buf (t+2)%3 whose
// readers (tile t-1) finished before tile t's start barrier. Steady wait: vmcnt(6).
__global__ __launch_bounds__(512, 1) void gemm_qkv_k(
    const unsigned short* __restrict__ A,     // Wqkv [1024][384]
    const unsigned short* __restrict__ Bt,    // xT   [b][4096][384]
    const float* __restrict__ bias,
    unsigned short* __restrict__ q_out,
    unsigned short* __restrict__ kv_out)
{
    __shared__ unsigned short As[3 * 8192];   // 3 bufs x 128 rows x 64 k
    __shared__ unsigned short Bs[3 * 16384];  // 3 bufs x 256 rows x 64 k
    const int tid = threadIdx.x;
    const int lane = tid & 63;
    const int w = tid >> 6, wr = w >> 2, wc = w & 3;
    const int li = lane & 15, g = lane >> 4;
    const int b = blockIdx.z;
    const int n0 = blockIdx.x * 256, m0 = blockIdx.y * 128;
    const unsigned short* Bb = Bt + (long)b * 4096 * 384;

#define STAGE_A(kt) { const int _bf = (kt) % 3; const int _k0 = (kt) * 64; \
    _Pragma("unroll") \
    for (int j = 0; j < 2; ++j) { \
        int idx = j * 512 + tid; \
        int r = idx >> 3; \
        int ls = ((idx & 7) ^ (r & 7)) * 8; \
        __builtin_amdgcn_global_load_lds( \
            (const __attribute__((address_space(1))) void*)(A + (long)(m0 + r) * 384 + _k0 + ls), \
            (__attribute__((address_space(3))) void*)(As + _bf * 8192 + (size_t)idx * 8), 16, 0, 0); \
    } }
#define STAGE_B(kt) { const int _bf = (kt) % 3; const int _k0 = (kt) * 64; \
    _Pragma("unroll") \
    for (int j = 0; j < 4; ++j) { \
        int idx = j * 512 + tid; \
        int r = idx >> 3; \
        int ls = ((idx & 7) ^ (r & 7)) * 8; \
        __builtin_amdgcn_global_load_lds( \
            (const __attribute__((address_space(1))) void*)(Bb + (long)(n0 + r) * 384 + _k0 + ls), \
            (__attribute__((address_space(3))) void*)(Bs + _bf * 16384 + (size_t)idx * 8), 16, 0, 0); \
    } }

    // prologue: stage tiles 0,1 (12 loads/thread in flight)
    STAGE_A(0); STAGE_B(0);
    STAGE_A(1); STAGE_B(1);

    f32x4 acc[4][4];
    #pragma unroll
    for (int i = 0; i < 4; ++i)
        #pragma unroll
        for (int j = 0; j < 4; ++j) acc[i][j] = (f32x4){0.f, 0.f, 0.f, 0.f};

    #pragma unroll
    for (int kt = 0; kt < 6; ++kt) {
        // tile-start: counted drain of tile kt's 6 loads; ONE barrier per K-tile
        if (kt < 5) asm volatile("s_waitcnt vmcnt(6)\n\ts_barrier" ::: "memory");
        else        asm volatile("s_waitcnt vmcnt(0)\n\ts_barrier" ::: "memory");

        const unsigned short* Ab = As + (kt % 3) * 8192;
        const unsigned short* Bl = Bs + (kt % 3) * 16384;

        #pragma unroll
        for (int kk = 0; kk < 2; ++kk) {
            bf16x8 av[4], bv[4];
            #pragma unroll
            for (int mf = 0; mf < 4; ++mf) {
                int r = wr * 64 + mf * 16 + li;
                av[mf] = *reinterpret_cast<const bf16x8*>(
                    Ab + r * 64 + (((kk * 4 + g) ^ (r & 7)) * 8));
            }
            #pragma unroll
            for (int nf = 0; nf < 4; ++nf) {
                int r = wc * 64 + nf * 16 + li;
                bv[nf] = *reinterpret_cast<const bf16x8*>(
                    Bl + r * 64 + (((kk * 4 + g) ^ (r & 7)) * 8));
            }
            if (kt < 4) { if (kk == 0) STAGE_A(kt + 2) else STAGE_B(kt + 2) }
            __builtin_amdgcn_s_setprio(1);
            #pragma unroll
            for (int mf = 0; mf < 4; ++mf)
                #pragma unroll
                for (int nf = 0; nf < 4; ++nf)
                    acc[mf][nf] = __builtin_amdgcn_mfma_f32_16x16x32_bf16(av[mf], bv[nf], acc[mf][nf], 0, 0, 0);
            __builtin_amdgcn_s_setprio(0);
        }
    }
#undef STAGE_A
#undef STAGE_B

    // ---- epilogue: m0<256 -> q (transposed packed), else k/v channel-major
    #pragma unroll
    for (int mf = 0; mf < 4; ++mf) {
        int m = m0 + wr * 64 + mf * 16 + g * 4;
        #pragma unroll
        for (int nf = 0; nf < 4; ++nf) {
            int n = n0 + wc * 64 + nf * 16 + li;
            f32x4 v = acc[mf][nf];
            if (m0 < 256) {
                us4 o = { f2bf(v.x + bias[m]),     f2bf(v.y + bias[m + 1]),
                          f2bf(v.z + bias[m + 2]), f2bf(v.w + bias[m + 3]) };
                *reinterpret_cast<us4*>(q_out + (((long)b * 4096 + n) << 8) + m) = o;
            } else {
                #pragma unroll
                for (int r = 0; r < 4; ++r)
                    kv_out[((long)b * 768 + (m - 256 + r)) * 4096 + n] = f2bf(v[r] + bias[m + r]);
            }
        }
    }
}

// ---------------- key row stats: max + 1/sum(exp) per k row ----------------
__global__ __launch_bounds__(256) void key_stats_k(const unsigned short* __restrict__ kv,
                                                   float2* __restrict__ kstats)
{
    __shared__ float red[256];
    const int row = blockIdx.x;             // 0..2047 = b*256 + ch
    const unsigned short* p = kv + ((long)(row >> 8) * 768 + (row & 255)) * 4096;
    const int tid = threadIdx.x;
    us4 u[4];
    float f[16];
    #pragma unroll
    for (int i = 0; i < 4; ++i) u[i] = *reinterpret_cast<const us4*>(p + tid * 16 + i * 4);
    float mx = -1e30f;
    #pragma unroll
    for (int i = 0; i < 4; ++i)
        #pragma unroll
        for (int j = 0; j < 4; ++j) { f[i * 4 + j] = bf2f(u[i][j]); mx = fmaxf(mx, f[i * 4 + j]); }
    red[tid] = mx; __syncthreads();
    for (int s = 128; s > 0; s >>= 1) { if (tid < s) red[tid] = fmaxf(red[tid], red[tid + s]); __syncthreads(); }
    mx = red[0]; __syncthreads();
    float sum = 0.f;
    #pragma unroll
    for (int i = 0; i < 16; ++i) sum += __expf(f[i] - mx);
    red[tid] = sum; __syncthreads();
    for (int s = 128; s > 0; s >>= 1) { if (tid < s) red[tid] += red[tid + s]; __syncthreads(); }
    if (tid == 0) kstats[row] = make_float2(mx, 1.f / red[0]);
}

// ---------------- context partials with in-register exp: part += exp(k-mx)*v ----------------
__global__ __launch_bounds__(256) void context_k(const unsigned short* __restrict__ kv,
                                                 const float2* __restrict__ kstats,
                                                 float* __restrict__ part)
{
    __shared__ float lds[4][2048];
    const int bh = blockIdx.y, ck = blockIdx.x;
    const int b = bh >> 3, h = bh & 7;
    const int tid = threadIdx.x, lane = tid & 63, w = tid >> 6;
    const int li = lane & 15, g = lane >> 4;
    const unsigned short* kb = kv + ((long)b * 768 + h * 32) * 4096;
    const unsigned short* vb = kv + ((long)b * 768 + 256 + h * 64) * 4096;
    const float mx0 = kstats[b * 256 + h * 32 + li].x;
    const float mx1 = kstats[b * 256 + h * 32 + 16 + li].x;
    f32x4 acc[2][4];
    #pragma unroll
    for (int i = 0; i < 2; ++i)
        #pragma unroll
        for (int j = 0; j < 4; ++j) acc[i][j] = (f32x4){0.f, 0.f, 0.f, 0.f};

    const int nb0 = ck * 512 + w * 128 + g * 8;
    #pragma unroll
    for (int t = 0; t < 4; ++t) {
        int nb = nb0 + t * 32;
        bf16x8 r0 = *reinterpret_cast<const bf16x8*>(kb + (long)li * 4096 + nb);
        bf16x8 r1 = *reinterpret_cast<const bf16x8*>(kb + (long)(16 + li) * 4096 + nb);
        bf16x8 a0, a1;
        #pragma unroll
        for (int j = 0; j < 8; ++j) {
            a0[j] = (short)f2bf(__expf(bf2f((unsigned short)r0[j]) - mx0));
            a1[j] = (short)f2bf(__expf(bf2f((unsigned short)r1[j]) - mx1));
        }
        #pragma unroll
        for (int nf = 0; nf < 4; ++nf) {
            bf16x8 bv = *reinterpret_cast<const bf16x8*>(vb + (long)(nf * 16 + li) * 4096 + nb);
            acc[0][nf] = __builtin_amdgcn_mfma_f32_16x16x32_bf16(a0, bv, acc[0][nf], 0, 0, 0);
            acc[1][nf] = __builtin_amdgcn_mfma_f32_16x16x32_bf16(a1, bv, acc[1][nf], 0, 0, 0);
        }
    }
    #pragma unroll
    for (int mf = 0; mf < 2; ++mf)
        #pragma unroll
        for (int nf = 0; nf < 4; ++nf)
            #pragma unroll
            for (int r = 0; r < 4; ++r) {
                int kd = mf * 16 + g * 4 + r, d = nf * 16 + li;
                lds[w][kd * 64 + d] = acc[mf][nf][r];
            }
    __syncthreads();
    for (int i = tid; i < 2048; i += 256)
        part[((long)ck * 64 + bh) * 2048 + i] = lds[0][i] + lds[1][i] + lds[2][i] + lds[3][i];
}

// ---------------- reduce partials, apply 1/sum -> ctxT[bh][d][kd] bf16 ----------------
__global__ __launch_bounds__(256) void ctx_reduce_k(const float* __restrict__ part,
                                                    const float2* __restrict__ kstats,
                                                    unsigned short* __restrict__ ctxT)
{
    int t = blockIdx.x * 256 + threadIdx.x;   // < 131072
    int bh = t >> 11, i = t & 2047;
    int kd = i & 31;
    float s = 0.f;
    #pragma unroll
    for (int c = 0; c < 8; ++c) s += part[((long)c * 64 + bh) * 2048 + kd * 64 + (i >> 5)];
    ctxT[t] = f2bf(s * kstats[bh * 32 + kd].y);
}

// ---------------- fused proj v3: tall-M block (M=384), softmax+attend once, GEMM ----------------
// grid (32 n-blocks, 8 b), 512 threads = 8 waves. LDS = 112 KB -> 1 block/CU.
__global__ __launch_bounds__(512, 2) void proj_fused_k(
    const unsigned short* __restrict__ Wpf,   // [384][512] bf16, k = h*64+d
    const unsigned short* __restrict__ qT,    // [b][4096][256] bf16 (raw q, pre-softmax)
    const unsigned short* __restrict__ ctxT,  // [b*8+h][64 d][32 kd] bf16
    const float* __restrict__ bp,
    float* __restrict__ out)                  // [b][384][4096] f32
{
    __shared__ unsigned short Bsh[128 * 64];  // relu(attend) tile for current head, swizzled
    __shared__ unsigned short As[2][384 * 64];
    const int tid = threadIdx.x, lane = tid & 63, w = tid >> 6;
    const int li = lane & 15, g = lane >> 4;
    const int b = blockIdx.y, n0 = blockIdx.x * 128;

#define PROJ_STAGE(buf, s) { \
    _Pragma("unroll") \
    for (int j = 0; j < 6; ++j) { \
        int idx = j * 512 + tid; \
        int r = idx >> 3; \
        int ls = ((idx & 7) ^ (r & 7)) * 8; \
        __builtin_amdgcn_global_load_lds( \
            (const __attribute__((address_space(1))) void*)(Wpf + (long)r * 512 + (s) * 64 + ls), \
            (__attribute__((address_space(3))) void*)(As[buf] + (size_t)idx * 8), 16, 0, 0); \
    } }

    PROJ_STAGE(0, 0);

    f32x4 acc[3][8];
    #pragma unroll
    for (int i = 0; i < 3; ++i)
        #pragma unroll
        for (int j = 0; j < 8; ++j) acc[i][j] = (f32x4){0.f, 0.f, 0.f, 0.f};

    for (int s = 0; s < 8; ++s) {               // K-step s == head s
        // ---- attend (once per block): A = ctxT_s, B = softmax(q) in-register.
        const unsigned short* cb = ctxT + ((long)b * 8 + s) * 2048;
        bf16x8 ca[4], pb;
        #pragma unroll
        for (int df = 0; df < 4; ++df)
            ca[df] = *reinterpret_cast<const bf16x8*>(cb + (df * 16 + li) * 32 + g * 8);
        {
            int n = n0 + w * 16 + li;
            bf16x8 r = *reinterpret_cast<const bf16x8*>(
                qT + (((long)b * 4096 + n) << 8) + s * 32 + g * 8);
            float f[8];
            float mx = -1e30f;
            #pragma unroll
            for (int j = 0; j < 8; ++j) { f[j] = bf2f((unsigned short)r[j]); mx = fmaxf(mx, f[j]); }
            mx = fmaxf(mx, __shfl_xor(mx, 16));
            mx = fmaxf(mx, __shfl_xor(mx, 32));
            float sm = 0.f;
            #pragma unroll
            for (int j = 0; j < 8; ++j) { f[j] = __expf(f[j] - mx); sm += f[j]; }
            sm += __shfl_xor(sm, 16);
            sm += __shfl_xor(sm, 32);
            float inv = 1.f / sm;
            #pragma unroll
            for (int j = 0; j < 8; ++j) pb[j] = (short)f2bf(f[j] * inv);
        }
        us4 bw[4];
        #pragma unroll
        for (int df = 0; df < 4; ++df) {
            f32x4 d = (f32x4){0.f, 0.f, 0.f, 0.f};
            d = __builtin_amdgcn_mfma_f32_16x16x32_bf16(ca[df], pb, d, 0, 0, 0);
            bw[df] = (us4){ f2bf(fmaxf(d.x, 0.f)), f2bf(fmaxf(d.y, 0.f)),
                            f2bf(fmaxf(d.z, 0.f)), f2bf(fmaxf(d.w, 0.f)) };
        }

        __syncthreads();   // (A) prior step's Bsh/As reads done; As[s&1] data landed (vmcnt0)

        if (s < 7) PROJ_STAGE((s + 1) & 1, s + 1);   // As[(s+1)&1] readers finished at (A)

        // ---- write relu(attend) tile swizzled: Bsh[n][d], granule-8 XOR by (n&7)
        #pragma unroll
        for (int df = 0; df < 4; ++df) {
            int n = w * 16 + li;
            int slot = (df * 2 + (g >> 1)) ^ (n & 7);
            *reinterpret_cast<us4*>(Bsh + n * 64 + slot * 8 + (g & 1) * 4) = bw[df];
        }

        // (B) lgkm-only barrier: Bsh visible, As[(s+1)&1] stage stays in flight (T4)
        asm volatile("s_waitcnt lgkmcnt(0)\n\ts_barrier" ::: "memory");
        __builtin_amdgcn_sched_barrier(0);

        // ---- main GEMM MFMAs: wave w owns m-rows w*48..w*48+48 x n 0..128
        const unsigned short* Ab = As[s & 1];
        #pragma unroll
        for (int kk = 0; kk < 2; ++kk) {
            bf16x8 av[3], bv[8];
            #pragma unroll
            for (int mf = 0; mf < 3; ++mf) {
                int row = w * 48 + mf * 16 + li;
                int ps = ((kk * 4 + g) ^ (row & 7)) * 8;
                av[mf] = *reinterpret_cast<const bf16x8*>(Ab + row * 64 + ps);
            }
            #pragma unroll
            for (int nf = 0; nf < 8; ++nf) {
                int nn = nf * 16 + li;
                int ps = ((kk * 4 + g) ^ (nn & 7)) * 8;
                bv[nf] = *reinterpret_cast<const bf16x8*>(Bsh + nn * 64 + ps);
            }
            #pragma unroll
            for (int mf = 0; mf < 3; ++mf)
                #pragma unroll
                for (int nf = 0; nf < 8; ++nf)
                    acc[mf][nf] = __builtin_amdgcn_mfma_f32_16x16x32_bf16(av[mf], bv[nf], acc[mf][nf], 0, 0, 0);
        }
    }
#undef PROJ_STAGE

    #pragma unroll
    for (int mf = 0; mf < 3; ++mf) {
        int m = w * 48 + mf * 16 + g * 4;
        #pragma unroll
        for (int nf = 0; nf < 8; ++nf) {
            int n = n0 + nf * 16 + li;
            f32x4 v = acc[mf][nf];
            #pragma unroll
            for (int r = 0; r < 4; ++r)
                out[((long)b * 384 + m + r) * 4096 + n] = v[r] + bp[m + r];
        }
    }
}

// ---------------- launch ----------------
extern "C" void kernel_launch(void* const* d_in, const int* in_sizes, int n_in,
                              void* d_out, int out_size, void* d_ws, size_t ws_size,
                              hipStream_t stream) {
    (void)in_sizes; (void)n_in; (void)out_size; (void)ws_size;
    const float* x  = (const float*)d_in[0];
    const float* Wq = (const float*)d_in[1];
    const float* sq = (const float*)d_in[2];
    const float* bq = (const float*)d_in[3];
    const float* Wk = (const float*)d_in[4];
    const float* sk = (const float*)d_in[5];
    const float* bk = (const float*)d_in[6];
    const float* Wv = (const float*)d_in[7];
    const float* sv = (const float*)d_in[8];
    const float* bv = (const float*)d_in[9];
    const float* Wp = (const float*)d_in[10];
    const float* sp = (const float*)d_in[11];
    const float* bp = (const float*)d_in[12];
    float* out = (float*)d_out;

    char* wsb = (char*)d_ws;
    unsigned short* Wqkv  = (unsigned short*)(wsb);              // 786432 B
    unsigned short* Wpf   = (unsigned short*)(wsb + 786432);     // 393216 B
    float*          bqkv  = (float*)(wsb + 1179648);             // 4096 B
    unsigned short* ctxT  = (unsigned short*)(wsb + 1183744);    // 262144 B
    float*          part  = (float*)(wsb + 1445888);             // 4194304 B
    float2*         kstats= (float2*)(wsb + 5640192);            // 16384 B
    unsigned short* xT    = (unsigned short*)(wsb + 5656576);    // 25165824 B
    unsigned short* qT    = (unsigned short*)(wsb + 30822400);   // 16777216 B
    unsigned short* kv    = (unsigned short*)(wsb + 47599616);   // 50331648 B -> ~98 MB total

    fold_weights_k<<<2308, 256, 0, stream>>>(Wq, sq, bq, Wk, sk, bk, Wv, sv, bv, Wp, sp,
                                             Wqkv, Wpf, bqkv);
    transpose_x_k<<<dim3(64, 6, 8), 256, 0, stream>>>(x, xT);
    gemm_qkv_k<<<dim3(16, 8, 8), 512, 0, stream>>>(Wqkv, xT, bqkv, qT, kv);
    key_stats_k<<<2048, 256, 0, stream>>>(kv, kstats);
    context_k<<<dim3(8, 64), 256, 0, stream>>>(kv, kstats, part);
    ctx_reduce_k<<<512, 256, 0, stream>>>(part, kstats, ctxT);
    proj_fused_k<<<dim3(32, 8), 512, 0, stream>>>(Wpf, qT, ctxT, bp, out);
}

// Round 8
// 115.712 us; speedup vs baseline: 1.0282x; 1.0262x over previous
//
#include <hip/hip_runtime.h>

typedef __attribute__((ext_vector_type(8))) short bf16x8;
typedef __attribute__((ext_vector_type(4))) float f32x4;
typedef __attribute__((ext_vector_type(4))) unsigned short us4;

__device__ __forceinline__ unsigned short f2bf(float f) {
    unsigned int u = __builtin_bit_cast(unsigned int, f);
    u = (u + 0x7FFFu + ((u >> 16) & 1u)) >> 16;
    return (unsigned short)u;
}
__device__ __forceinline__ float bf2f(unsigned short h) {
    return __builtin_bit_cast(float, (unsigned int)h << 16);
}

// ---------------- fold BN into weights, emit bf16 ----------------
__global__ __launch_bounds__(256) void fold_weights_k(
    const float* __restrict__ Wq, const float* __restrict__ sq, const float* __restrict__ bq,
    const float* __restrict__ Wk, const float* __restrict__ sk, const float* __restrict__ bk,
    const float* __restrict__ Wv, const float* __restrict__ sv, const float* __restrict__ bv,
    const float* __restrict__ Wp, const float* __restrict__ sp,
    unsigned short* __restrict__ Wqkv, unsigned short* __restrict__ Wpf, float* __restrict__ bqkv)
{
    int i = blockIdx.x * 256 + threadIdx.x;
    if (i < 393216) {                       // Wqkv [1024][384]
        int o = i / 384;
        float w, s;
        if (o < 256)      { w = Wq[i];                s = sq[o]; }
        else if (o < 512) { w = Wk[i - 256 * 384];    s = sk[o - 256]; }
        else              { w = Wv[i - 512 * 384];    s = sv[o - 512]; }
        Wqkv[i] = f2bf(w * s);
    } else if (i < 589824) {                // Wpf [384][512]
        int j = i - 393216;
        Wpf[j] = f2bf(Wp[j] * sp[j >> 9]);
    } else if (i < 590848) {
        int o = i - 589824;
        bqkv[o] = (o < 256) ? bq[o] : (o < 512 ? bk[o - 256] : bv[o - 512]);
    }
}

// ---------------- x [b][384][4096] f32 -> xT [b][4096][384] bf16 (vectorized) ----------------
__global__ __launch_bounds__(256) void transpose_x_k(const float* __restrict__ x,
                                                     unsigned short* __restrict__ xT)
{
    __shared__ unsigned short t[64][72];
    const int b = blockIdx.z, cb = blockIdx.y << 6, nb = blockIdx.x << 6;
    const int tid = threadIdx.x;
    const float* xb = x + ((long)b * 384 + cb) * 4096 + nb;
    const int n4 = (tid & 15) * 4;
    #pragma unroll
    for (int p = 0; p < 4; ++p) {
        int c = (tid >> 4) + p * 16;
        float4 v = *reinterpret_cast<const float4*>(xb + (long)c * 4096 + n4);
        us4 o = { f2bf(v.x), f2bf(v.y), f2bf(v.z), f2bf(v.w) };
        *reinterpret_cast<us4*>(&t[c][n4]) = o;
    }
    __syncthreads();
    const int c4 = (tid & 15) * 4;
    unsigned short* ob = xT + ((long)b * 4096 + nb) * 384 + cb;
    #pragma unroll
    for (int p = 0; p < 4; ++p) {
        int n = (tid >> 4) + p * 16;
        us4 o = { t[c4][n], t[c4 + 1][n], t[c4 + 2][n], t[c4 + 3][n] };
        *reinterpret_cast<us4*>(ob + (long)n * 384 + c4) = o;
    }
}

// ---------------- QKV GEMM: 128x128 tile, BK=32 row-pair-packed LDS, 3-buf depth-2 ----------------
// grid (32 n, 8 m, 8 b), 256 threads = 4 waves (2M x 2N), wave tile 64x64.
// LDS = 3 bufs x (A 8KB + B 8KB) = 48 KB -> 3 blocks/CU = 12 waves/CU.
// Row-pair packing: logical (r,k) lives in lds row p=r>>1 (128B rows), granule
// slot = ((r&1)*4 + k/8) ^ (p&7)  -- same 128B-row XOR geometry measured conflict-free.
// Tile t in buf t%3; stage t+2 during t; tile-start wait vmcnt(4) (never 0 until last).
__global__ __launch_bounds__(256, 4) void gemm_qkv_k(
    const unsigned short* __restrict__ A,     // Wqkv [1024][384]
    const unsigned short* __restrict__ Bt,    // xT   [b][4096][384]
    const float* __restrict__ bias,
    unsigned short* __restrict__ q_out,
    unsigned short* __restrict__ kv_out)
{
    __shared__ unsigned short As[3 * 4096];   // 3 x 128 rows x 32 k (8 KB)
    __shared__ unsigned short Bs[3 * 4096];
    const int tid = threadIdx.x;
    const int lane = tid & 63;
    const int w = tid >> 6, wr = w >> 1, wc = w & 1;
    const int li = lane & 15, g = lane >> 4;
    const int b = blockIdx.z;
    const int n0 = blockIdx.x * 128, m0 = blockIdx.y * 128;
    const unsigned short* Bb = Bt + (long)b * 4096 * 384;

    // staging granule map (inverse of read swizzle): granule i -> (row, k-slice)
    const int i0 = tid, i1 = tid + 256;
    const int p0 = i0 >> 3, v0 = (i0 & 7) ^ (p0 & 7);
    const int p1 = i1 >> 3, v1 = (i1 & 7) ^ (p1 & 7);
    const long ro0 = (long)(p0 * 2 + (v0 >> 2)) * 384 + (v0 & 3) * 8;
    const long ro1 = (long)(p1 * 2 + (v1 >> 2)) * 384 + (v1 & 3) * 8;
    const long aro0 = (long)m0 * 384 + ro0, aro1 = (long)m0 * 384 + ro1;
    const long bro0 = (long)n0 * 384 + ro0, bro1 = (long)n0 * 384 + ro1;

#define STAGE(kt) { const int _bf = (kt) % 3; const int _k0 = (kt) * 32; \
    __builtin_amdgcn_global_load_lds( \
        (const __attribute__((address_space(1))) void*)(A + aro0 + _k0), \
        (__attribute__((address_space(3))) void*)(As + _bf * 4096 + (size_t)i0 * 8), 16, 0, 0); \
    __builtin_amdgcn_global_load_lds( \
        (const __attribute__((address_space(1))) void*)(A + aro1 + _k0), \
        (__attribute__((address_space(3))) void*)(As + _bf * 4096 + (size_t)i1 * 8), 16, 0, 0); \
    __builtin_amdgcn_global_load_lds( \
        (const __attribute__((address_space(1))) void*)(Bb + bro0 + _k0), \
        (__attribute__((address_space(3))) void*)(Bs + _bf * 4096 + (size_t)i0 * 8), 16, 0, 0); \
    __builtin_amdgcn_global_load_lds( \
        (const __attribute__((address_space(1))) void*)(Bb + bro1 + _k0), \
        (__attribute__((address_space(3))) void*)(Bs + _bf * 4096 + (size_t)i1 * 8), 16, 0, 0); }

    // prologue: stage tiles 0 and 1 (8 loads/thread in flight)
    STAGE(0); STAGE(1);

    f32x4 acc[4][4];
    #pragma unroll
    for (int i = 0; i < 4; ++i)
        #pragma unroll
        for (int j = 0; j < 4; ++j) acc[i][j] = (f32x4){0.f, 0.f, 0.f, 0.f};

    #pragma unroll
    for (int kt = 0; kt < 12; ++kt) {
        // counted drain of tile kt's 4 loads (tile kt+1's stay in flight)
        if (kt < 11) asm volatile("s_waitcnt vmcnt(4)\n\ts_barrier" ::: "memory");
        else         asm volatile("s_waitcnt vmcnt(0)\n\ts_barrier" ::: "memory");

        const unsigned short* Ab = As + (kt % 3) * 4096;
        const unsigned short* Bl = Bs + (kt % 3) * 4096;

        bf16x8 av[4], bv[4];
        #pragma unroll
        for (int mf = 0; mf < 4; ++mf) {
            int r = wr * 64 + mf * 16 + li;
            int p = r >> 1;
            int slot = (((r & 1) * 4 + g) ^ (p & 7));
            av[mf] = *reinterpret_cast<const bf16x8*>(Ab + p * 64 + slot * 8);
        }
        #pragma unroll
        for (int nf = 0; nf < 4; ++nf) {
            int r = wc * 64 + nf * 16 + li;
            int p = r >> 1;
            int slot = (((r & 1) * 4 + g) ^ (p & 7));
            bv[nf] = *reinterpret_cast<const bf16x8*>(Bl + p * 64 + slot * 8);
        }
        if (kt < 10) STAGE(kt + 2);
        __builtin_amdgcn_s_setprio(1);
        #pragma unroll
        for (int mf = 0; mf < 4; ++mf)
            #pragma unroll
            for (int nf = 0; nf < 4; ++nf)
                acc[mf][nf] = __builtin_amdgcn_mfma_f32_16x16x32_bf16(av[mf], bv[nf], acc[mf][nf], 0, 0, 0);
        __builtin_amdgcn_s_setprio(0);
    }
#undef STAGE

    // ---- epilogue: m0<256 -> q (transposed packed), else k/v channel-major
    #pragma unroll
    for (int mf = 0; mf < 4; ++mf) {
        int m = m0 + wr * 64 + mf * 16 + g * 4;
        #pragma unroll
        for (int nf = 0; nf < 4; ++nf) {
            int n = n0 + wc * 64 + nf * 16 + li;
            f32x4 v = acc[mf][nf];
            if (m0 < 256) {
                us4 o = { f2bf(v.x + bias[m]),     f2bf(v.y + bias[m + 1]),
                          f2bf(v.z + bias[m + 2]), f2bf(v.w + bias[m + 3]) };
                *reinterpret_cast<us4*>(q_out + (((long)b * 4096 + n) << 8) + m) = o;
            } else {
                #pragma unroll
                for (int r = 0; r < 4; ++r)
                    kv_out[((long)b * 768 + (m - 256 + r)) * 4096 + n] = f2bf(v[r] + bias[m + r]);
            }
        }
    }
}

// ---------------- key row stats: max + 1/sum(exp) per k row ----------------
__global__ __launch_bounds__(256) void key_stats_k(const unsigned short* __restrict__ kv,
                                                   float2* __restrict__ kstats)
{
    __shared__ float red[256];
    const int row = blockIdx.x;             // 0..2047 = b*256 + ch
    const unsigned short* p = kv + ((long)(row >> 8) * 768 + (row & 255)) * 4096;
    const int tid = threadIdx.x;
    us4 u[4];
    float f[16];
    #pragma unroll
    for (int i = 0; i < 4; ++i) u[i] = *reinterpret_cast<const us4*>(p + tid * 16 + i * 4);
    float mx = -1e30f;
    #pragma unroll
    for (int i = 0; i < 4; ++i)
        #pragma unroll
        for (int j = 0; j < 4; ++j) { f[i * 4 + j] = bf2f(u[i][j]); mx = fmaxf(mx, f[i * 4 + j]); }
    red[tid] = mx; __syncthreads();
    for (int s = 128; s > 0; s >>= 1) { if (tid < s) red[tid] = fmaxf(red[tid], red[tid + s]); __syncthreads(); }
    mx = red[0]; __syncthreads();
    float sum = 0.f;
    #pragma unroll
    for (int i = 0; i < 16; ++i) sum += __expf(f[i] - mx);
    red[tid] = sum; __syncthreads();
    for (int s = 128; s > 0; s >>= 1) { if (tid < s) red[tid] += red[tid + s]; __syncthreads(); }
    if (tid == 0) kstats[row] = make_float2(mx, 1.f / red[0]);
}

// ---------------- context partials with in-register exp: part += exp(k-mx)*v ----------------
__global__ __launch_bounds__(256) void context_k(const unsigned short* __restrict__ kv,
                                                 const float2* __restrict__ kstats,
                                                 float* __restrict__ part)
{
    __shared__ float lds[4][2048];
    const int bh = blockIdx.y, ck = blockIdx.x;
    const int b = bh >> 3, h = bh & 7;
    const int tid = threadIdx.x, lane = tid & 63, w = tid >> 6;
    const int li = lane & 15, g = lane >> 4;
    const unsigned short* kb = kv + ((long)b * 768 + h * 32) * 4096;
    const unsigned short* vb = kv + ((long)b * 768 + 256 + h * 64) * 4096;
    const float mx0 = kstats[b * 256 + h * 32 + li].x;
    const float mx1 = kstats[b * 256 + h * 32 + 16 + li].x;
    f32x4 acc[2][4];
    #pragma unroll
    for (int i = 0; i < 2; ++i)
        #pragma unroll
        for (int j = 0; j < 4; ++j) acc[i][j] = (f32x4){0.f, 0.f, 0.f, 0.f};

    const int nb0 = ck * 512 + w * 128 + g * 8;
    #pragma unroll
    for (int t = 0; t < 4; ++t) {
        int nb = nb0 + t * 32;
        bf16x8 r0 = *reinterpret_cast<const bf16x8*>(kb + (long)li * 4096 + nb);
        bf16x8 r1 = *reinterpret_cast<const bf16x8*>(kb + (long)(16 + li) * 4096 + nb);
        bf16x8 a0, a1;
        #pragma unroll
        for (int j = 0; j < 8; ++j) {
            a0[j] = (short)f2bf(__expf(bf2f((unsigned short)r0[j]) - mx0));
            a1[j] = (short)f2bf(__expf(bf2f((unsigned short)r1[j]) - mx1));
        }
        #pragma unroll
        for (int nf = 0; nf < 4; ++nf) {
            bf16x8 bv = *reinterpret_cast<const bf16x8*>(vb + (long)(nf * 16 + li) * 4096 + nb);
            acc[0][nf] = __builtin_amdgcn_mfma_f32_16x16x32_bf16(a0, bv, acc[0][nf], 0, 0, 0);
            acc[1][nf] = __builtin_amdgcn_mfma_f32_16x16x32_bf16(a1, bv, acc[1][nf], 0, 0, 0);
        }
    }
    #pragma unroll
    for (int mf = 0; mf < 2; ++mf)
        #pragma unroll
        for (int nf = 0; nf < 4; ++nf)
            #pragma unroll
            for (int r = 0; r < 4; ++r) {
                int kd = mf * 16 + g * 4 + r, d = nf * 16 + li;
                lds[w][kd * 64 + d] = acc[mf][nf][r];
            }
    __syncthreads();
    for (int i = tid; i < 2048; i += 256)
        part[((long)ck * 64 + bh) * 2048 + i] = lds[0][i] + lds[1][i] + lds[2][i] + lds[3][i];
}

// ---------------- reduce partials, apply 1/sum -> ctxT[bh][d][kd] bf16 ----------------
__global__ __launch_bounds__(256) void ctx_reduce_k(const float* __restrict__ part,
                                                    const float2* __restrict__ kstats,
                                                    unsigned short* __restrict__ ctxT)
{
    int t = blockIdx.x * 256 + threadIdx.x;   // < 131072
    int bh = t >> 11, i = t & 2047;
    int kd = i & 31;
    float s = 0.f;
    #pragma unroll
    for (int c = 0; c < 8; ++c) s += part[((long)c * 64 + bh) * 2048 + kd * 64 + (i >> 5)];
    ctxT[t] = f2bf(s * kstats[bh * 32 + kd].y);
}

// ---------------- fused proj v3: tall-M block (M=384), softmax+attend once, GEMM ----------------
// grid (32 n-blocks, 8 b), 512 threads = 8 waves. LDS = 112 KB -> 1 block/CU.
__global__ __launch_bounds__(512, 2) void proj_fused_k(
    const unsigned short* __restrict__ Wpf,   // [384][512] bf16, k = h*64+d
    const unsigned short* __restrict__ qT,    // [b][4096][256] bf16 (raw q, pre-softmax)
    const unsigned short* __restrict__ ctxT,  // [b*8+h][64 d][32 kd] bf16
    const float* __restrict__ bp,
    float* __restrict__ out)                  // [b][384][4096] f32
{
    __shared__ unsigned short Bsh[128 * 64];  // relu(attend) tile for current head, swizzled
    __shared__ unsigned short As[2][384 * 64];
    const int tid = threadIdx.x, lane = tid & 63, w = tid >> 6;
    const int li = lane & 15, g = lane >> 4;
    const int b = blockIdx.y, n0 = blockIdx.x * 128;

#define PROJ_STAGE(buf, s) { \
    _Pragma("unroll") \
    for (int j = 0; j < 6; ++j) { \
        int idx = j * 512 + tid; \
        int r = idx >> 3; \
        int ls = ((idx & 7) ^ (r & 7)) * 8; \
        __builtin_amdgcn_global_load_lds( \
            (const __attribute__((address_space(1))) void*)(Wpf + (long)r * 512 + (s) * 64 + ls), \
            (__attribute__((address_space(3))) void*)(As[buf] + (size_t)idx * 8), 16, 0, 0); \
    } }

    PROJ_STAGE(0, 0);

    f32x4 acc[3][8];
    #pragma unroll
    for (int i = 0; i < 3; ++i)
        #pragma unroll
        for (int j = 0; j < 8; ++j) acc[i][j] = (f32x4){0.f, 0.f, 0.f, 0.f};

    for (int s = 0; s < 8; ++s) {               // K-step s == head s
        // ---- attend (once per block): A = ctxT_s, B = softmax(q) in-register.
        const unsigned short* cb = ctxT + ((long)b * 8 + s) * 2048;
        bf16x8 ca[4], pb;
        #pragma unroll
        for (int df = 0; df < 4; ++df)
            ca[df] = *reinterpret_cast<const bf16x8*>(cb + (df * 16 + li) * 32 + g * 8);
        {
            int n = n0 + w * 16 + li;
            bf16x8 r = *reinterpret_cast<const bf16x8*>(
                qT + (((long)b * 4096 + n) << 8) + s * 32 + g * 8);
            float f[8];
            float mx = -1e30f;
            #pragma unroll
            for (int j = 0; j < 8; ++j) { f[j] = bf2f((unsigned short)r[j]); mx = fmaxf(mx, f[j]); }
            mx = fmaxf(mx, __shfl_xor(mx, 16));
            mx = fmaxf(mx, __shfl_xor(mx, 32));
            float sm = 0.f;
            #pragma unroll
            for (int j = 0; j < 8; ++j) { f[j] = __expf(f[j] - mx); sm += f[j]; }
            sm += __shfl_xor(sm, 16);
            sm += __shfl_xor(sm, 32);
            float inv = 1.f / sm;
            #pragma unroll
            for (int j = 0; j < 8; ++j) pb[j] = (short)f2bf(f[j] * inv);
        }
        us4 bw[4];
        #pragma unroll
        for (int df = 0; df < 4; ++df) {
            f32x4 d = (f32x4){0.f, 0.f, 0.f, 0.f};
            d = __builtin_amdgcn_mfma_f32_16x16x32_bf16(ca[df], pb, d, 0, 0, 0);
            bw[df] = (us4){ f2bf(fmaxf(d.x, 0.f)), f2bf(fmaxf(d.y, 0.f)),
                            f2bf(fmaxf(d.z, 0.f)), f2bf(fmaxf(d.w, 0.f)) };
        }

        __syncthreads();   // (A) prior step's Bsh/As reads done; As[s&1] data landed (vmcnt0)

        if (s < 7) PROJ_STAGE((s + 1) & 1, s + 1);   // As[(s+1)&1] readers finished at (A)

        // ---- write relu(attend) tile swizzled: Bsh[n][d], granule-8 XOR by (n&7)
        #pragma unroll
        for (int df = 0; df < 4; ++df) {
            int n = w * 16 + li;
            int slot = (df * 2 + (g >> 1)) ^ (n & 7);
            *reinterpret_cast<us4*>(Bsh + n * 64 + slot * 8 + (g & 1) * 4) = bw[df];
        }

        // (B) lgkm-only barrier: Bsh visible, As[(s+1)&1] stage stays in flight (T4)
        asm volatile("s_waitcnt lgkmcnt(0)\n\ts_barrier" ::: "memory");
        __builtin_amdgcn_sched_barrier(0);

        // ---- main GEMM MFMAs: wave w owns m-rows w*48..w*48+48 x n 0..128
        const unsigned short* Ab = As[s & 1];
        #pragma unroll
        for (int kk = 0; kk < 2; ++kk) {
            bf16x8 av[3], bv[8];
            #pragma unroll
            for (int mf = 0; mf < 3; ++mf) {
                int row = w * 48 + mf * 16 + li;
                int ps = ((kk * 4 + g) ^ (row & 7)) * 8;
                av[mf] = *reinterpret_cast<const bf16x8*>(Ab + row * 64 + ps);
            }
            #pragma unroll
            for (int nf = 0; nf < 8; ++nf) {
                int nn = nf * 16 + li;
                int ps = ((kk * 4 + g) ^ (nn & 7)) * 8;
                bv[nf] = *reinterpret_cast<const bf16x8*>(Bsh + nn * 64 + ps);
            }
            #pragma unroll
            for (int mf = 0; mf < 3; ++mf)
                #pragma unroll
                for (int nf = 0; nf < 8; ++nf)
                    acc[mf][nf] = __builtin_amdgcn_mfma_f32_16x16x32_bf16(av[mf], bv[nf], acc[mf][nf], 0, 0, 0);
        }
    }
#undef PROJ_STAGE

    #pragma unroll
    for (int mf = 0; mf < 3; ++mf) {
        int m = w * 48 + mf * 16 + g * 4;
        #pragma unroll
        for (int nf = 0; nf < 8; ++nf) {
            int n = n0 + nf * 16 + li;
            f32x4 v = acc[mf][nf];
            #pragma unroll
            for (int r = 0; r < 4; ++r)
                out[((long)b * 384 + m + r) * 4096 + n] = v[r] + bp[m + r];
        }
    }
}

// ---------------- launch ----------------
extern "C" void kernel_launch(void* const* d_in, const int* in_sizes, int n_in,
                              void* d_out, int out_size, void* d_ws, size_t ws_size,
                              hipStream_t stream) {
    (void)in_sizes; (void)n_in; (void)out_size; (void)ws_size;
    const float* x  = (const float*)d_in[0];
    const float* Wq = (const float*)d_in[1];
    const float* sq = (const float*)d_in[2];
    const float* bq = (const float*)d_in[3];
    const float* Wk = (const float*)d_in[4];
    const float* sk = (const float*)d_in[5];
    const float* bk = (const float*)d_in[6];
    const float* Wv = (const float*)d_in[7];
    const float* sv = (const float*)d_in[8];
    const float* bv = (const float*)d_in[9];
    const float* Wp = (const float*)d_in[10];
    const float* sp = (const float*)d_in[11];
    const float* bp = (const float*)d_in[12];
    float* out = (float*)d_out;

    char* wsb = (char*)d_ws;
    unsigned short* Wqkv  = (unsigned short*)(wsb);              // 786432 B
    unsigned short* Wpf   = (unsigned short*)(wsb + 786432);     // 393216 B
    float*          bqkv  = (float*)(wsb + 1179648);             // 4096 B
    unsigned short* ctxT  = (unsigned short*)(wsb + 1183744);    // 262144 B
    float*          part  = (float*)(wsb + 1445888);             // 4194304 B
    float2*         kstats= (float2*)(wsb + 5640192);            // 16384 B
    unsigned short* xT    = (unsigned short*)(wsb + 5656576);    // 25165824 B
    unsigned short* qT    = (unsigned short*)(wsb + 30822400);   // 16777216 B
    unsigned short* kv    = (unsigned short*)(wsb + 47599616);   // 50331648 B -> ~98 MB total

    fold_weights_k<<<2308, 256, 0, stream>>>(Wq, sq, bq, Wk, sk, bk, Wv, sv, bv, Wp, sp,
                                             Wqkv, Wpf, bqkv);
    transpose_x_k<<<dim3(64, 6, 8), 256, 0, stream>>>(x, xT);
    gemm_qkv_k<<<dim3(32, 8, 8), 256, 0, stream>>>(Wqkv, xT, bqkv, qT, kv);
    key_stats_k<<<2048, 256, 0, stream>>>(kv, kstats);
    context_k<<<dim3(8, 64), 256, 0, stream>>>(kv, kstats, part);
    ctx_reduce_k<<<512, 256, 0, stream>>>(part, kstats, ctxT);
    proj_fused_k<<<dim3(32, 8), 512, 0, stream>>>(Wpf, qT, ctxT, bp, out);
}